// Round 18
// baseline (79.744 us; speedup 1.0000x reference)
//
#include <hip/hip_runtime.h>
#include <hip/hip_bf16.h>
#include <hip/hip_fp16.h>

#define NN 100000
#define EE 1600000
#define ET (EE + NN)            // edges incl. self loops
#define HID 64
#define NEG 0.2f
#define NBUK 391                // ceil(NN/256) buckets of 256 dst nodes
#define SCT_TILE 8192           // edges per block in scatter phase (1024 thr x 8)
#define BUKCAP 8192             // padded per-bucket capacity (mean 4352, sigma~66)

__device__ __forceinline__ float uh(unsigned u) {
    __half_raw r; r.x = (unsigned short)(u & 0xFFFF);
    return __half2float(__half(r));
}
__device__ __forceinline__ unsigned f2h(float f) {
    __half h = __float2half_rn(f);
    __half_raw r = *reinterpret_cast<__half_raw*>(&h);
    return (unsigned)r.x;
}

// ---------------- kernel 0: rec[n] = {ss1 f32, x[5] f16}; sd1; zero bcur; 2 nodes/wave ----------------
__global__ __launch_bounds__(256) void k_proj(const float* __restrict__ x,
                                              const float* __restrict__ W1,
                                              const float* __restrict__ a_src1,
                                              const float* __restrict__ a_dst1,
                                              unsigned* __restrict__ rec,
                                              float* __restrict__ sd1,
                                              int* __restrict__ bcur) {
    if (blockIdx.x == 0) {
        for (int i = threadIdx.x; i < 1024; i += 256) bcur[i] = 0;
    }
    int wid  = threadIdx.x >> 6;
    int lane = threadIdx.x & 63;
    int half = lane >> 5, li = lane & 31;
    int n = (blockIdx.x * 4 + wid) * 2 + half;
    if (n >= NN) return;
    float xv[5];
    float h0 = 0.f, h1 = 0.f;
#pragma unroll
    for (int k = 0; k < 5; ++k) {
        xv[k] = x[n * 5 + k];
        h0 += xv[k] * W1[k * HID + li];
        h1 += xv[k] * W1[k * HID + li + 32];
    }
    float a = h0 * a_src1[li] + h1 * a_src1[li + 32];
    float b = h0 * a_dst1[li] + h1 * a_dst1[li + 32];
#pragma unroll
    for (int o = 1; o <= 16; o <<= 1) { a += __shfl_xor(a, o); b += __shfl_xor(b, o); }
    if (li == 0) {
        sd1[n] = b;
        uint4 rv;
        rv.x = __float_as_uint(a);
        rv.y = f2h(xv[0]) | (f2h(xv[1]) << 16);
        rv.z = f2h(xv[2]) | (f2h(xv[3]) << 16);
        rv.w = f2h(xv[4]);
        *(uint4*)(rec + (size_t)n * 4) = rv;
    }
}

// ---------------- CSR scatter: 1024 threads, 8 edges/thread, bid-ushort flush ----------------
__global__ __launch_bounds__(1024) void k_bscatter(const int* __restrict__ ei,
                                                   int* __restrict__ bcur,
                                                   unsigned* __restrict__ pairs) {
    __shared__ unsigned sp[SCT_TILE];
    __shared__ unsigned short bid[SCT_TILE];
    __shared__ int cnt_[NBUK], loc[NBUK], cur[NBUK];
    __shared__ int wsum[16];
    int tid = threadIdx.x;
    int wid = tid >> 6, lane = tid & 63;
    int base = blockIdx.x * SCT_TILE;
    int tilecnt = ET - base; if (tilecnt > SCT_TILE) tilecnt = SCT_TILE;

    for (int i = tid; i < NBUK; i += 1024) cnt_[i] = 0;
    __syncthreads();
    // single pass: int4 edge loads + rank atomic (rank kept in registers)
    int sreg[8], dreg[8], rreg[8];
#pragma unroll
    for (int it = 0; it < 2; ++it) {
        int i = base + (it * 1024 + tid) * 4;
        if (i + 3 < EE) {
            const int4 sv = *(const int4*)(ei + i);
            const int4 dv = *(const int4*)(ei + EE + i);
            sreg[it*4+0] = sv.x; sreg[it*4+1] = sv.y; sreg[it*4+2] = sv.z; sreg[it*4+3] = sv.w;
            dreg[it*4+0] = dv.x; dreg[it*4+1] = dv.y; dreg[it*4+2] = dv.z; dreg[it*4+3] = dv.w;
        } else {
#pragma unroll
            for (int k = 0; k < 4; ++k) {
                int idx = i + k;
                if (idx < EE)      { sreg[it*4+k] = ei[idx];  dreg[it*4+k] = ei[EE + idx]; }
                else if (idx < ET) { sreg[it*4+k] = idx - EE; dreg[it*4+k] = idx - EE; }
                else               { dreg[it*4+k] = -1; }
            }
        }
#pragma unroll
        for (int k = 0; k < 4; ++k)
            if (dreg[it*4+k] >= 0) rreg[it*4+k] = atomicAdd(&cnt_[dreg[it*4+k] >> 8], 1);
    }
    __syncthreads();
    // exclusive scan of cnt_ -> loc: 4 bins/thread, wave shuffle scan, cross-wave fixup
    int b0 = tid * 4;
    int s0 = 0;
    if (b0 < NBUK)
        for (int k = 0; k < 4 && b0 + k < NBUK; ++k) s0 += cnt_[b0 + k];
    int incl = s0;
#pragma unroll
    for (int o = 1; o < 64; o <<= 1) {
        int t = __shfl(incl, (lane - o) & 63);
        if (lane >= o) incl += t;
    }
    if (lane == 63) wsum[wid] = incl;
    __syncthreads();
    int wpref = 0;
    for (int w = 0; w < wid; ++w) wpref += wsum[w];
    if (b0 < NBUK) {
        int run = wpref + incl - s0;
        for (int k = 0; k < 4 && b0 + k < NBUK; ++k) {
            loc[b0 + k] = run;
            run += cnt_[b0 + k];
        }
    }
    __syncthreads();
    // reserve global space; fold (global_start - local_start) so addr = cur[b] + slot
    for (int i = tid; i < NBUK; i += 1024) {
        int c = cnt_[i];
        cur[i] = c ? (atomicAdd(&bcur[i], c) + i * BUKCAP - loc[i]) : 0;
    }
    __syncthreads();
    // placement: plain LDS writes at loc[b] + rank
#pragma unroll
    for (int q = 0; q < 8; ++q) {
        if (dreg[q] >= 0) {
            int s = sreg[q], d = dreg[q];
            int b = d >> 8;
            int slot = loc[b] + rreg[q];
            sp[slot]  = ((unsigned)(d & 255) << 17) | (unsigned)s;
            bid[slot] = (unsigned short)b;
        }
    }
    __syncthreads();
    // flush (runs of ~21 consecutive slots per bucket -> consecutive global)
    for (int i = tid; i < tilecnt; i += 1024)
        pairs[cur[bid[i]] + i] = sp[i];
}

// ---------------- fused: per-bucket counting sort (srt in LDS) + layer-1 aggregate ----------------
__device__ __forceinline__ void agg1_gen_lds(int n, int lane, int off, int deg,
                                             const int* srt,
                                             const unsigned* __restrict__ rec,
                                             const float* __restrict__ sd1,
                                             const float* __restrict__ W1,
                                             const float* __restrict__ b1,
                                             const float* __restrict__ W2,
                                             float* __restrict__ h2) {
    bool valid = n < NN;
    float sdn = valid ? sd1[n] : 0.f;
    float dsum = 0.f, a0 = 0.f, a1 = 0.f, a2 = 0.f, a3 = 0.f, a4 = 0.f;
    for (int j0 = 0; j0 < deg; j0 += 64) {
        int j = j0 + lane;
        if (j < deg) {
            int s = srt[off + j];
            const uint4 v = *(const uint4*)(rec + (size_t)s * 4);
            float t = __uint_as_float(v.x) + sdn;
            float e = t > 0.f ? t : NEG * t;
            float w = __expf(e);
            dsum += w;
            a0 += w * uh(v.y); a1 += w * uh(v.y >> 16);
            a2 += w * uh(v.z); a3 += w * uh(v.z >> 16);
            a4 += w * uh(v.w);
        }
    }
#pragma unroll
    for (int o = 32; o; o >>= 1) {
        dsum += __shfl_xor(dsum, o);
        a0 += __shfl_xor(a0, o); a1 += __shfl_xor(a1, o); a2 += __shfl_xor(a2, o);
        a3 += __shfl_xor(a3, o); a4 += __shfl_xor(a4, o);
    }
    float inv = 1.0f / dsum;
    a0 *= inv; a1 *= inv; a2 *= inv; a3 *= inv; a4 *= inv;
    float of = b1[lane] + a0 * W1[lane] + a1 * W1[64 + lane] + a2 * W1[128 + lane]
             + a3 * W1[192 + lane] + a4 * W1[256 + lane];
    of = fmaxf(of, 0.f);
    float p2 = of * W2[lane];
#pragma unroll
    for (int o = 32; o; o >>= 1) p2 += __shfl_xor(p2, o);
    if (lane == 0 && valid) h2[n] = p2;
}

__global__ __launch_bounds__(1024) void k_sortagg(const int* __restrict__ bcur,
                                                  unsigned* __restrict__ pairs,
                                                  int* __restrict__ rowptr,
                                                  int* __restrict__ cntd,
                                                  const unsigned* __restrict__ rec,
                                                  const float* __restrict__ sd1,
                                                  const float* __restrict__ W1,
                                                  const float* __restrict__ b1,
                                                  const float* __restrict__ W2,
                                                  float* __restrict__ h2) {
    __shared__ int srt[BUKCAP];     // 32KB: sorted src list for this bucket
    __shared__ int hist[256], sc[256];
    int b = blockIdx.x;
    int cnt = bcur[b];
    if (cnt > BUKCAP) cnt = BUKCAP;
    int base = b * BUKCAP;
    int tid = threadIdx.x;
    if (tid < 256) hist[tid] = 0;
    __syncthreads();
    // pass 1: vectorized read (8 contiguous pairs/thread), rank-atomic, registers
    unsigned preg[8];
    int rreg[8];
    int i0 = tid * 8;
    if (i0 + 8 <= cnt) {
        const uint4 v0 = *(const uint4*)(pairs + base + i0);
        const uint4 v1 = *(const uint4*)(pairs + base + i0 + 4);
        preg[0] = v0.x; preg[1] = v0.y; preg[2] = v0.z; preg[3] = v0.w;
        preg[4] = v1.x; preg[5] = v1.y; preg[6] = v1.z; preg[7] = v1.w;
    } else {
#pragma unroll
        for (int j = 0; j < 8; ++j)
            preg[j] = (i0 + j < cnt) ? pairs[base + i0 + j] : 0xFFFFFFFFu;
    }
#pragma unroll
    for (int j = 0; j < 8; ++j)
        if (preg[j] != 0xFFFFFFFFu) rreg[j] = atomicAdd(&hist[preg[j] >> 17], 1);
    __syncthreads();
    // 256-bin exclusive scan on wave 0 (4 bins/lane)
    if (tid < 64) {
        int v0 = hist[4 * tid], v1 = hist[4 * tid + 1];
        int v2 = hist[4 * tid + 2], v3 = hist[4 * tid + 3];
        int s = v0 + v1 + v2 + v3;
#pragma unroll
        for (int o = 1; o < 64; o <<= 1) {
            int t = __shfl(s, (tid - o) & 63);
            if (tid >= o) s += t;
        }
        int excl = s - v0 - v1 - v2 - v3;
        sc[4 * tid]     = excl;
        sc[4 * tid + 1] = excl + v0;
        sc[4 * tid + 2] = excl + v0 + v1;
        sc[4 * tid + 3] = excl + v0 + v1 + v2;
    }
    __syncthreads();
    int nbase = b << 8;
    if (tid < 256 && nbase + tid < NN) {
        rowptr[nbase + tid] = base + sc[tid];
        cntd[nbase + tid]   = hist[tid];
    }
    // sorted scatter: srt (LDS, consumed below) + adj (global, for k_agg2)
    int* adj = (int*)pairs;   // aliases pairs; all pairs reads completed above
#pragma unroll
    for (int j = 0; j < 8; ++j) {
        if (preg[j] != 0xFFFFFFFFu) {
            int ld = (int)(preg[j] >> 17);
            int pos = sc[ld] + rreg[j];
            int s = (int)(preg[j] & 0x1FFFF);
            srt[pos] = s;
            adj[base + pos] = s;
        }
    }
    __syncthreads();

    // ---- aggregation: 16 waves x 8 node-pairs over 256 nodes ----
    int wid  = tid >> 6;
    int lane = tid & 63;
    for (int pp = wid; pp < 128; pp += 16) {
        int l0 = pp * 2, l1 = pp * 2 + 1;
        int d0 = hist[l0], d1 = hist[l1];
        if (d0 <= 32 && d1 <= 32) {
            int half = lane >> 5, li = lane & 31;
            int ln = half ? l1 : l0;
            int n = nbase + ln;
            bool valid = n < NN;
            int deg = half ? d1 : d0;
            int off = sc[ln];
            float sdn = valid ? sd1[n] : 0.f;
            int s = srt[off + (li < deg ? li : 0)];
            if (deg == 0) s = 0;
            const uint4 v = *(const uint4*)(rec + (size_t)s * 4);
            float t = __uint_as_float(v.x) + sdn;
            float e = t > 0.f ? t : NEG * t;
            float p = (li < deg) ? __expf(e) : 0.f;
            float ds = p;
            float a0 = p * uh(v.y), a1 = p * uh(v.y >> 16);
            float a2 = p * uh(v.z), a3 = p * uh(v.z >> 16);
            float a4 = p * uh(v.w);
#pragma unroll
            for (int o = 1; o <= 16; o <<= 1) {
                ds += __shfl_xor(ds, o);
                a0 += __shfl_xor(a0, o); a1 += __shfl_xor(a1, o); a2 += __shfl_xor(a2, o);
                a3 += __shfl_xor(a3, o); a4 += __shfl_xor(a4, o);
            }
            float inv = 1.0f / ds;
            a0 *= inv; a1 *= inv; a2 *= inv; a3 *= inv; a4 *= inv;
            float o0 = b1[li] + a0 * W1[li] + a1 * W1[64 + li] + a2 * W1[128 + li]
                     + a3 * W1[192 + li] + a4 * W1[256 + li];
            float o1 = b1[li + 32] + a0 * W1[li + 32] + a1 * W1[96 + li] + a2 * W1[160 + li]
                     + a3 * W1[224 + li] + a4 * W1[288 + li];
            o0 = fmaxf(o0, 0.f);
            o1 = fmaxf(o1, 0.f);
            float p2 = o0 * W2[li] + o1 * W2[li + 32];
#pragma unroll
            for (int o = 1; o <= 16; o <<= 1) p2 += __shfl_xor(p2, o);
            if (li == 0 && valid) h2[n] = p2;
        } else {
            agg1_gen_lds(nbase + l0, lane, sc[l0], d0, srt, rec, sd1, W1, b1, W2, h2);
            agg1_gen_lds(nbase + l1, lane, sc[l1], d1, srt, rec, sd1, W1, b1, W2, h2);
        }
    }
}

// ---------------- layer 2: full-wave single-node fallback (no max, single pass) ----------------
__device__ __forceinline__ void agg2_node(int n, int lane,
                                          const int* __restrict__ rowptr,
                                          const int* __restrict__ cntd,
                                          const int* __restrict__ adj,
                                          const float* __restrict__ h2,
                                          float as2v, float ad2v, float b2v,
                                          float* __restrict__ out) {
    int off = rowptr[n], deg = cntd[n];
    float sdn = h2[n] * ad2v;
    float dsum = 0.f, nsum = 0.f;
    for (int j0 = 0; j0 < deg; j0 += 64) {
        int j = j0 + lane;
        if (j < deg) {
            int s = adj[off + j];
            float hv = h2[s];
            float e = hv * as2v + sdn;
            e = e > 0.f ? e : NEG * e;
            float ex = __expf(e);
            dsum += ex;
            nsum += ex * hv;
        }
    }
#pragma unroll
    for (int o = 32; o; o >>= 1) { dsum += __shfl_xor(dsum, o); nsum += __shfl_xor(nsum, o); }
    if (lane == 0) out[n] = nsum / dsum + b2v;
}

// ---------------- layer 2: 4 nodes per wave, no max ----------------
__global__ __launch_bounds__(256) void k_agg2(const int* __restrict__ rowptr,
                                              const int* __restrict__ cntd,
                                              const int* __restrict__ adj,
                                              const float* __restrict__ h2,
                                              const float* __restrict__ as2,
                                              const float* __restrict__ ad2,
                                              const float* __restrict__ b2,
                                              float* __restrict__ out) {
    int wid  = threadIdx.x >> 6;
    int lane = threadIdx.x & 63;
    int n0 = (blockIdx.x * 4 + wid) * 4;
    if (n0 >= NN) return;
    float as2v = as2[0], ad2v = ad2[0], b2v = b2[0];
    int d0 = cntd[n0], d1 = cntd[n0 + 1], d2 = cntd[n0 + 2], d3 = cntd[n0 + 3];

    if (d0 <= 32 && d1 <= 32 && d2 <= 32 && d3 <= 32) {
        int half = lane >> 5, li = lane & 31;
        int nA = n0 + half, nB = n0 + 2 + half;
        int offA = rowptr[nA], offB = rowptr[nB];
        int degA = half ? d1 : d0, degB = half ? d3 : d2;
        float sdA = h2[nA] * ad2v, sdB = h2[nB] * ad2v;
        float hvA = 0.f, hvB = 0.f, pA = 0.f, pB = 0.f;
        if (li < degA) {
            hvA = h2[adj[offA + li]];
            float t = hvA * as2v + sdA;
            pA = __expf(t > 0.f ? t : NEG * t);
        }
        if (li < degB) {
            hvB = h2[adj[offB + li]];
            float t = hvB * as2v + sdB;
            pB = __expf(t > 0.f ? t : NEG * t);
        }
        float dsA = pA, dsB = pB, nsA = pA * hvA, nsB = pB * hvB;
#pragma unroll
        for (int o = 1; o <= 16; o <<= 1) {
            dsA += __shfl_xor(dsA, o); nsA += __shfl_xor(nsA, o);
            dsB += __shfl_xor(dsB, o); nsB += __shfl_xor(nsB, o);
        }
        if (li == 0) {
            out[nA] = nsA / dsA + b2v;
            out[nB] = nsB / dsB + b2v;
        }
    } else {
        agg2_node(n0,     lane, rowptr, cntd, adj, h2, as2v, ad2v, b2v, out);
        agg2_node(n0 + 1, lane, rowptr, cntd, adj, h2, as2v, ad2v, b2v, out);
        agg2_node(n0 + 2, lane, rowptr, cntd, adj, h2, as2v, ad2v, b2v, out);
        agg2_node(n0 + 3, lane, rowptr, cntd, adj, h2, as2v, ad2v, b2v, out);
    }
}

extern "C" void kernel_launch(void* const* d_in, const int* in_sizes, int n_in,
                              void* d_out, int out_size, void* d_ws, size_t ws_size,
                              hipStream_t stream) {
    const float* x      = (const float*)d_in[0];
    const int*   ei     = (const int*)d_in[1];
    const float* W1     = (const float*)d_in[2];
    const float* a_src1 = (const float*)d_in[3];
    const float* a_dst1 = (const float*)d_in[4];
    const float* b1     = (const float*)d_in[5];
    const float* W2     = (const float*)d_in[6];
    const float* as2    = (const float*)d_in[7];
    const float* ad2    = (const float*)d_in[8];
    const float* b2     = (const float*)d_in[9];
    float* out = (float*)d_out;

    // workspace layout (all 4-byte elements)
    unsigned* rec = (unsigned*)d_ws;                    // N*4 words = 1.6MB
    float* sd1  = (float*)(rec + (size_t)NN * 4);       // N
    float* h2   = sd1 + NN;                             // N
    int* rowptr = (int*)(h2 + NN);                      // N
    int* cntd   = rowptr + NN;                          // N
    int* bcur   = cntd + NN;                            // 1024
    unsigned* pairs = (unsigned*)(bcur + 1024);         // NBUK*BUKCAP = 12.8MB (reused as adj)
    int* adj    = (int*)pairs;

    const int NSCT = (ET + SCT_TILE - 1) / SCT_TILE;    // 208
    const int NPROJ = (NN / 2 + 3) / 4;                 // 12500 blocks, 2 nodes/wave
    const int NQUAD = (NN + 15) / 16;                   // 6250 blocks, 4 nodes/wave

    k_proj<<<NPROJ, 256, 0, stream>>>(x, W1, a_src1, a_dst1, rec, sd1, bcur);
    k_bscatter<<<NSCT, 1024, 0, stream>>>(ei, bcur, pairs);
    k_sortagg<<<NBUK, 1024, 0, stream>>>(bcur, pairs, rowptr, cntd, rec, sd1, W1, b1, W2, h2);
    k_agg2<<<NQUAD, 256, 0, stream>>>(rowptr, cntd, adj, h2, as2, ad2, b2, out);
}

// Round 19
// 77.414 us; speedup vs baseline: 1.0301x; 1.0301x over previous
//
#include <hip/hip_runtime.h>
#include <hip/hip_bf16.h>
#include <hip/hip_fp16.h>

#define NN 100000
#define EE 1600000
#define ET (EE + NN)            // edges incl. self loops
#define HID 64
#define NEG 0.2f
#define NBUK 391                // ceil(NN/256) buckets of 256 dst nodes
#define SCT_TILE 8192           // edges per block in scatter phase (1024 thr x 8)
#define BUKCAP 8192             // padded per-bucket capacity (mean 4352, sigma~66)

__device__ __forceinline__ float uh(unsigned u) {
    __half_raw r; r.x = (unsigned short)(u & 0xFFFF);
    return __half2float(__half(r));
}
__device__ __forceinline__ unsigned f2h(float f) {
    __half h = __float2half_rn(f);
    __half_raw r = *reinterpret_cast<__half_raw*>(&h);
    return (unsigned)r.x;
}

// ---------------- kernel 0: rec[n] = {ss1 f32, x[5] f16}; sd1; zero bcur; 2 nodes/wave ----------------
__global__ __launch_bounds__(256) void k_proj(const float* __restrict__ x,
                                              const float* __restrict__ W1,
                                              const float* __restrict__ a_src1,
                                              const float* __restrict__ a_dst1,
                                              unsigned* __restrict__ rec,
                                              float* __restrict__ sd1,
                                              int* __restrict__ bcur) {
    if (blockIdx.x == 0) {
        for (int i = threadIdx.x; i < 1024; i += 256) bcur[i] = 0;
    }
    int wid  = threadIdx.x >> 6;
    int lane = threadIdx.x & 63;
    int half = lane >> 5, li = lane & 31;
    int n = (blockIdx.x * 4 + wid) * 2 + half;
    if (n >= NN) return;
    float xv[5];
    float h0 = 0.f, h1 = 0.f;
#pragma unroll
    for (int k = 0; k < 5; ++k) {
        xv[k] = x[n * 5 + k];
        h0 += xv[k] * W1[k * HID + li];
        h1 += xv[k] * W1[k * HID + li + 32];
    }
    float a = h0 * a_src1[li] + h1 * a_src1[li + 32];
    float b = h0 * a_dst1[li] + h1 * a_dst1[li + 32];
#pragma unroll
    for (int o = 1; o <= 16; o <<= 1) { a += __shfl_xor(a, o); b += __shfl_xor(b, o); }
    if (li == 0) {
        sd1[n] = b;
        uint4 rv;
        rv.x = __float_as_uint(a);
        rv.y = f2h(xv[0]) | (f2h(xv[1]) << 16);
        rv.z = f2h(xv[2]) | (f2h(xv[3]) << 16);
        rv.w = f2h(xv[4]);
        *(uint4*)(rec + (size_t)n * 4) = rv;
    }
}

// ---------------- CSR scatter: 1024 threads, 8 edges/thread, bid-ushort flush ----------------
__global__ __launch_bounds__(1024) void k_bscatter(const int* __restrict__ ei,
                                                   int* __restrict__ bcur,
                                                   unsigned* __restrict__ pairs) {
    __shared__ unsigned sp[SCT_TILE];
    __shared__ unsigned short bid[SCT_TILE];
    __shared__ int cnt_[NBUK], loc[NBUK], cur[NBUK];
    __shared__ int wsum[16];
    int tid = threadIdx.x;
    int wid = tid >> 6, lane = tid & 63;
    int base = blockIdx.x * SCT_TILE;
    int tilecnt = ET - base; if (tilecnt > SCT_TILE) tilecnt = SCT_TILE;

    for (int i = tid; i < NBUK; i += 1024) cnt_[i] = 0;
    __syncthreads();
    // single pass: int4 edge loads + rank atomic (rank kept in registers)
    int sreg[8], dreg[8], rreg[8];
#pragma unroll
    for (int it = 0; it < 2; ++it) {
        int i = base + (it * 1024 + tid) * 4;
        if (i + 3 < EE) {
            const int4 sv = *(const int4*)(ei + i);
            const int4 dv = *(const int4*)(ei + EE + i);
            sreg[it*4+0] = sv.x; sreg[it*4+1] = sv.y; sreg[it*4+2] = sv.z; sreg[it*4+3] = sv.w;
            dreg[it*4+0] = dv.x; dreg[it*4+1] = dv.y; dreg[it*4+2] = dv.z; dreg[it*4+3] = dv.w;
        } else {
#pragma unroll
            for (int k = 0; k < 4; ++k) {
                int idx = i + k;
                if (idx < EE)      { sreg[it*4+k] = ei[idx];  dreg[it*4+k] = ei[EE + idx]; }
                else if (idx < ET) { sreg[it*4+k] = idx - EE; dreg[it*4+k] = idx - EE; }
                else               { dreg[it*4+k] = -1; }
            }
        }
#pragma unroll
        for (int k = 0; k < 4; ++k)
            if (dreg[it*4+k] >= 0) rreg[it*4+k] = atomicAdd(&cnt_[dreg[it*4+k] >> 8], 1);
    }
    __syncthreads();
    // exclusive scan of cnt_ -> loc: 4 bins/thread, wave shuffle scan, cross-wave fixup
    int b0 = tid * 4;
    int s0 = 0;
    if (b0 < NBUK)
        for (int k = 0; k < 4 && b0 + k < NBUK; ++k) s0 += cnt_[b0 + k];
    int incl = s0;
#pragma unroll
    for (int o = 1; o < 64; o <<= 1) {
        int t = __shfl(incl, (lane - o) & 63);
        if (lane >= o) incl += t;
    }
    if (lane == 63) wsum[wid] = incl;
    __syncthreads();
    int wpref = 0;
    for (int w = 0; w < wid; ++w) wpref += wsum[w];
    if (b0 < NBUK) {
        int run = wpref + incl - s0;
        for (int k = 0; k < 4 && b0 + k < NBUK; ++k) {
            loc[b0 + k] = run;
            run += cnt_[b0 + k];
        }
    }
    __syncthreads();
    // reserve global space; fold (global_start - local_start) so addr = cur[b] + slot
    for (int i = tid; i < NBUK; i += 1024) {
        int c = cnt_[i];
        cur[i] = c ? (atomicAdd(&bcur[i], c) + i * BUKCAP - loc[i]) : 0;
    }
    __syncthreads();
    // placement: plain LDS writes at loc[b] + rank
#pragma unroll
    for (int q = 0; q < 8; ++q) {
        if (dreg[q] >= 0) {
            int s = sreg[q], d = dreg[q];
            int b = d >> 8;
            int slot = loc[b] + rreg[q];
            sp[slot]  = ((unsigned)(d & 255) << 17) | (unsigned)s;
            bid[slot] = (unsigned short)b;
        }
    }
    __syncthreads();
    // flush (runs of ~21 consecutive slots per bucket -> consecutive global)
    for (int i = tid; i < tilecnt; i += 1024)
        pairs[cur[bid[i]] + i] = sp[i];
}

// ---------------- per-bucket counting sort: uint4 reads, 1 rank-atomic/edge ----------------
__global__ __launch_bounds__(1024) void k_bsort(const int* __restrict__ bcur,
                                                unsigned* __restrict__ pairs,
                                                int* __restrict__ rowptr,
                                                int* __restrict__ cntd) {
    __shared__ int hist[256], sc[256];
    int b = blockIdx.x;
    int cnt = bcur[b];
    if (cnt > BUKCAP) cnt = BUKCAP;
    int base = b * BUKCAP;
    int tid = threadIdx.x;
    if (tid < 256) hist[tid] = 0;
    __syncthreads();
    // pass 1: vectorized read (8 contiguous pairs/thread), rank-atomic, registers
    unsigned preg[8];
    int rreg[8];
    int i0 = tid * 8;
    if (i0 + 8 <= cnt) {
        const uint4 v0 = *(const uint4*)(pairs + base + i0);
        const uint4 v1 = *(const uint4*)(pairs + base + i0 + 4);
        preg[0] = v0.x; preg[1] = v0.y; preg[2] = v0.z; preg[3] = v0.w;
        preg[4] = v1.x; preg[5] = v1.y; preg[6] = v1.z; preg[7] = v1.w;
    } else {
#pragma unroll
        for (int j = 0; j < 8; ++j)
            preg[j] = (i0 + j < cnt) ? pairs[base + i0 + j] : 0xFFFFFFFFu;
    }
#pragma unroll
    for (int j = 0; j < 8; ++j)
        if (preg[j] != 0xFFFFFFFFu) rreg[j] = atomicAdd(&hist[preg[j] >> 17], 1);
    __syncthreads();
    // 256-bin exclusive scan on wave 0 (4 bins/lane)
    if (tid < 64) {
        int v0 = hist[4 * tid], v1 = hist[4 * tid + 1];
        int v2 = hist[4 * tid + 2], v3 = hist[4 * tid + 3];
        int s = v0 + v1 + v2 + v3;
#pragma unroll
        for (int o = 1; o < 64; o <<= 1) {
            int t = __shfl(s, (tid - o) & 63);
            if (tid >= o) s += t;
        }
        int excl = s - v0 - v1 - v2 - v3;
        sc[4 * tid]     = excl;
        sc[4 * tid + 1] = excl + v0;
        sc[4 * tid + 2] = excl + v0 + v1;
        sc[4 * tid + 3] = excl + v0 + v1 + v2;
    }
    __syncthreads();
    int nbase = b << 8;
    if (tid < 256 && nbase + tid < NN) {
        rowptr[nbase + tid] = base + sc[tid];
        cntd[nbase + tid]   = hist[tid];
    }
    // pass 2: direct sorted write (adj aliases pairs; all reads completed pre-barrier)
    int* adj = (int*)pairs;
#pragma unroll
    for (int j = 0; j < 8; ++j) {
        if (preg[j] != 0xFFFFFFFFu) {
            int ld = (int)(preg[j] >> 17);
            adj[base + sc[ld] + rreg[j]] = (int)(preg[j] & 0x1FFFF);
        }
    }
}

// ---------------- layer 1 generic fallback (deg>32): single pass, no max, 16B record ----------------
__device__ __forceinline__ void agg1_node_gen(int n, int lane,
                                              const int* __restrict__ rowptr,
                                              const int* __restrict__ cntd,
                                              const int* __restrict__ adj,
                                              const unsigned* __restrict__ rec,
                                              const float* __restrict__ sd1,
                                              const float* __restrict__ W1,
                                              const float* __restrict__ b1,
                                              const float* __restrict__ W2,
                                              float* __restrict__ h2) {
    int off = rowptr[n], deg = cntd[n];
    float sdn = sd1[n];
    float dsum = 0.f, a0 = 0.f, a1 = 0.f, a2 = 0.f, a3 = 0.f, a4 = 0.f;
    for (int j0 = 0; j0 < deg; j0 += 64) {
        int j = j0 + lane;
        if (j < deg) {
            int s = adj[off + j];
            const uint4 v = *(const uint4*)(rec + (size_t)s * 4);
            float t = __uint_as_float(v.x) + sdn;
            float e = t > 0.f ? t : NEG * t;
            float w = __expf(e);
            dsum += w;
            a0 += w * uh(v.y); a1 += w * uh(v.y >> 16);
            a2 += w * uh(v.z); a3 += w * uh(v.z >> 16);
            a4 += w * uh(v.w);
        }
    }
#pragma unroll
    for (int o = 32; o; o >>= 1) {
        dsum += __shfl_xor(dsum, o);
        a0 += __shfl_xor(a0, o); a1 += __shfl_xor(a1, o); a2 += __shfl_xor(a2, o);
        a3 += __shfl_xor(a3, o); a4 += __shfl_xor(a4, o);
    }
    float inv = 1.0f / dsum;
    a0 *= inv; a1 *= inv; a2 *= inv; a3 *= inv; a4 *= inv;
    float of = b1[lane] + a0 * W1[lane] + a1 * W1[64 + lane] + a2 * W1[128 + lane]
             + a3 * W1[192 + lane] + a4 * W1[256 + lane];
    of = fmaxf(of, 0.f);
    float p2 = of * W2[lane];
#pragma unroll
    for (int o = 32; o; o >>= 1) p2 += __shfl_xor(p2, o);
    if (lane == 0) h2[n] = p2;
}

// ---------------- layer 1: lane=edge, 2 nodes per wave, no max, ONE 16B gather/edge ----------------
__global__ __launch_bounds__(256) void k_agg1(const int* __restrict__ rowptr,
                                              const int* __restrict__ cntd,
                                              const int* __restrict__ adj,
                                              const unsigned* __restrict__ rec,
                                              const float* __restrict__ sd1,
                                              const float* __restrict__ W1,
                                              const float* __restrict__ b1,
                                              const float* __restrict__ W2,
                                              float* __restrict__ h2) {
    int wid  = threadIdx.x >> 6;
    int lane = threadIdx.x & 63;
    int n0 = (blockIdx.x * 4 + wid) * 2;
    if (n0 >= NN) return;
    int d0 = cntd[n0], d1 = cntd[n0 + 1];

    if (d0 <= 32 && d1 <= 32) {
        int half = lane >> 5, li = lane & 31;
        int n = n0 + half;
        int off = rowptr[n];
        int deg = half ? d1 : d0;
        float sdn = sd1[n];
        int s = adj[off + (li < deg ? li : 0)];
        const uint4 v = *(const uint4*)(rec + (size_t)s * 4);
        float t = __uint_as_float(v.x) + sdn;
        float e = t > 0.f ? t : NEG * t;
        float p = (li < deg) ? __expf(e) : 0.f;
        float ds = p;
        float a0 = p * uh(v.y), a1 = p * uh(v.y >> 16);
        float a2 = p * uh(v.z), a3 = p * uh(v.z >> 16);
        float a4 = p * uh(v.w);
#pragma unroll
        for (int o = 1; o <= 16; o <<= 1) {
            ds += __shfl_xor(ds, o);
            a0 += __shfl_xor(a0, o); a1 += __shfl_xor(a1, o); a2 += __shfl_xor(a2, o);
            a3 += __shfl_xor(a3, o); a4 += __shfl_xor(a4, o);
        }
        float inv = 1.0f / ds;
        a0 *= inv; a1 *= inv; a2 *= inv; a3 *= inv; a4 *= inv;
        float o0 = b1[li] + a0 * W1[li] + a1 * W1[64 + li] + a2 * W1[128 + li]
                 + a3 * W1[192 + li] + a4 * W1[256 + li];
        float o1 = b1[li + 32] + a0 * W1[li + 32] + a1 * W1[96 + li] + a2 * W1[160 + li]
                 + a3 * W1[224 + li] + a4 * W1[288 + li];
        o0 = fmaxf(o0, 0.f);
        o1 = fmaxf(o1, 0.f);
        float p2 = o0 * W2[li] + o1 * W2[li + 32];
#pragma unroll
        for (int o = 1; o <= 16; o <<= 1) p2 += __shfl_xor(p2, o);
        if (li == 0) h2[n] = p2;
    } else {
        agg1_node_gen(n0,     lane, rowptr, cntd, adj, rec, sd1, W1, b1, W2, h2);
        agg1_node_gen(n0 + 1, lane, rowptr, cntd, adj, rec, sd1, W1, b1, W2, h2);
    }
}

// ---------------- layer 2: full-wave single-node fallback (no max, single pass) ----------------
__device__ __forceinline__ void agg2_node(int n, int lane,
                                          const int* __restrict__ rowptr,
                                          const int* __restrict__ cntd,
                                          const int* __restrict__ adj,
                                          const float* __restrict__ h2,
                                          float as2v, float ad2v, float b2v,
                                          float* __restrict__ out) {
    int off = rowptr[n], deg = cntd[n];
    float sdn = h2[n] * ad2v;
    float dsum = 0.f, nsum = 0.f;
    for (int j0 = 0; j0 < deg; j0 += 64) {
        int j = j0 + lane;
        if (j < deg) {
            int s = adj[off + j];
            float hv = h2[s];
            float e = hv * as2v + sdn;
            e = e > 0.f ? e : NEG * e;
            float ex = __expf(e);
            dsum += ex;
            nsum += ex * hv;
        }
    }
#pragma unroll
    for (int o = 32; o; o >>= 1) { dsum += __shfl_xor(dsum, o); nsum += __shfl_xor(nsum, o); }
    if (lane == 0) out[n] = nsum / dsum + b2v;
}

// ---------------- layer 2: 4 nodes per wave, no max ----------------
__global__ __launch_bounds__(256) void k_agg2(const int* __restrict__ rowptr,
                                              const int* __restrict__ cntd,
                                              const int* __restrict__ adj,
                                              const float* __restrict__ h2,
                                              const float* __restrict__ as2,
                                              const float* __restrict__ ad2,
                                              const float* __restrict__ b2,
                                              float* __restrict__ out) {
    int wid  = threadIdx.x >> 6;
    int lane = threadIdx.x & 63;
    int n0 = (blockIdx.x * 4 + wid) * 4;
    if (n0 >= NN) return;
    float as2v = as2[0], ad2v = ad2[0], b2v = b2[0];
    int d0 = cntd[n0], d1 = cntd[n0 + 1], d2 = cntd[n0 + 2], d3 = cntd[n0 + 3];

    if (d0 <= 32 && d1 <= 32 && d2 <= 32 && d3 <= 32) {
        int half = lane >> 5, li = lane & 31;
        int nA = n0 + half, nB = n0 + 2 + half;
        int offA = rowptr[nA], offB = rowptr[nB];
        int degA = half ? d1 : d0, degB = half ? d3 : d2;
        float sdA = h2[nA] * ad2v, sdB = h2[nB] * ad2v;
        float hvA = 0.f, hvB = 0.f, pA = 0.f, pB = 0.f;
        if (li < degA) {
            hvA = h2[adj[offA + li]];
            float t = hvA * as2v + sdA;
            pA = __expf(t > 0.f ? t : NEG * t);
        }
        if (li < degB) {
            hvB = h2[adj[offB + li]];
            float t = hvB * as2v + sdB;
            pB = __expf(t > 0.f ? t : NEG * t);
        }
        float dsA = pA, dsB = pB, nsA = pA * hvA, nsB = pB * hvB;
#pragma unroll
        for (int o = 1; o <= 16; o <<= 1) {
            dsA += __shfl_xor(dsA, o); nsA += __shfl_xor(nsA, o);
            dsB += __shfl_xor(dsB, o); nsB += __shfl_xor(nsB, o);
        }
        if (li == 0) {
            out[nA] = nsA / dsA + b2v;
            out[nB] = nsB / dsB + b2v;
        }
    } else {
        agg2_node(n0,     lane, rowptr, cntd, adj, h2, as2v, ad2v, b2v, out);
        agg2_node(n0 + 1, lane, rowptr, cntd, adj, h2, as2v, ad2v, b2v, out);
        agg2_node(n0 + 2, lane, rowptr, cntd, adj, h2, as2v, ad2v, b2v, out);
        agg2_node(n0 + 3, lane, rowptr, cntd, adj, h2, as2v, ad2v, b2v, out);
    }
}

extern "C" void kernel_launch(void* const* d_in, const int* in_sizes, int n_in,
                              void* d_out, int out_size, void* d_ws, size_t ws_size,
                              hipStream_t stream) {
    const float* x      = (const float*)d_in[0];
    const int*   ei     = (const int*)d_in[1];
    const float* W1     = (const float*)d_in[2];
    const float* a_src1 = (const float*)d_in[3];
    const float* a_dst1 = (const float*)d_in[4];
    const float* b1     = (const float*)d_in[5];
    const float* W2     = (const float*)d_in[6];
    const float* as2    = (const float*)d_in[7];
    const float* ad2    = (const float*)d_in[8];
    const float* b2     = (const float*)d_in[9];
    float* out = (float*)d_out;

    // workspace layout (all 4-byte elements)
    unsigned* rec = (unsigned*)d_ws;                    // N*4 words = 1.6MB
    float* sd1  = (float*)(rec + (size_t)NN * 4);       // N
    float* h2   = sd1 + NN;                             // N
    int* rowptr = (int*)(h2 + NN);                      // N
    int* cntd   = rowptr + NN;                          // N
    int* bcur   = cntd + NN;                            // 1024
    unsigned* pairs = (unsigned*)(bcur + 1024);         // NBUK*BUKCAP = 12.8MB (reused as adj)
    int* adj    = (int*)pairs;

    const int NSCT = (ET + SCT_TILE - 1) / SCT_TILE;    // 208
    const int NPROJ = (NN / 2 + 3) / 4;                 // 12500 blocks, 2 nodes/wave
    const int NPAIR = (NN / 2 + 3) / 4;                 // 12500 blocks, 2 nodes/wave
    const int NQUAD = (NN + 15) / 16;                   // 6250 blocks, 4 nodes/wave

    k_proj<<<NPROJ, 256, 0, stream>>>(x, W1, a_src1, a_dst1, rec, sd1, bcur);
    k_bscatter<<<NSCT, 1024, 0, stream>>>(ei, bcur, pairs);
    k_bsort<<<NBUK, 1024, 0, stream>>>(bcur, pairs, rowptr, cntd);
    k_agg1<<<NPAIR, 256, 0, stream>>>(rowptr, cntd, adj, rec, sd1, W1, b1, W2, h2);
    k_agg2<<<NQUAD, 256, 0, stream>>>(rowptr, cntd, adj, h2, as2, ad2, b2, out);
}

// Round 20
// 76.297 us; speedup vs baseline: 1.0452x; 1.0146x over previous
//
#include <hip/hip_runtime.h>
#include <hip/hip_bf16.h>
#include <hip/hip_fp16.h>

#define NN 100000
#define EE 1600000
#define ET (EE + NN)            // edges incl. self loops
#define HID 64
#define NEG 0.2f
#define NBUK 391                // ceil(NN/256) buckets of 256 dst nodes
#define SCT_TILE 8192           // edges per block in scatter phase (1024 thr x 8)
#define BUKCAP 8192             // padded per-bucket capacity (mean 4352, sigma~66)

__device__ __forceinline__ float uh(unsigned u) {
    __half_raw r; r.x = (unsigned short)(u & 0xFFFF);
    return __half2float(__half(r));
}
__device__ __forceinline__ unsigned f2h(float f) {
    __half h = __float2half_rn(f);
    __half_raw r = *reinterpret_cast<__half_raw*>(&h);
    return (unsigned)r.x;
}

#define NSCT ((ET + SCT_TILE - 1) / SCT_TILE)   // 208 scatter-role blocks
#define NPROJB ((NN + 31) / 32)                 // 3125 proj-role blocks (32 nodes each)

// ---------------- merged front kernel: scatter role (blocks < NSCT) + proj role ----------------
__global__ __launch_bounds__(1024) void k_front(const float* __restrict__ x,
                                                const float* __restrict__ W1,
                                                const float* __restrict__ a_src1,
                                                const float* __restrict__ a_dst1,
                                                const int* __restrict__ ei,
                                                unsigned* __restrict__ rec,
                                                float* __restrict__ sd1,
                                                int* __restrict__ bcur,
                                                unsigned* __restrict__ pairs) {
    __shared__ unsigned sp[SCT_TILE];
    __shared__ unsigned short bid[SCT_TILE];
    __shared__ int cnt_[NBUK], loc[NBUK], cur[NBUK];
    __shared__ int wsum[16];
    int tid = threadIdx.x;

    if (blockIdx.x >= NSCT) {
        // ---- proj role: 16 waves x 2 nodes = 32 nodes per block ----
        int p = blockIdx.x - NSCT;
        int wid  = tid >> 6;
        int half = (tid >> 5) & 1, li = tid & 31;
        int n = p * 32 + wid * 2 + half;
        if (n >= NN) return;
        float xv[5];
        float h0 = 0.f, h1 = 0.f;
#pragma unroll
        for (int k = 0; k < 5; ++k) {
            xv[k] = x[n * 5 + k];
            h0 += xv[k] * W1[k * HID + li];
            h1 += xv[k] * W1[k * HID + li + 32];
        }
        float a = h0 * a_src1[li] + h1 * a_src1[li + 32];
        float b = h0 * a_dst1[li] + h1 * a_dst1[li + 32];
#pragma unroll
        for (int o = 1; o <= 16; o <<= 1) { a += __shfl_xor(a, o); b += __shfl_xor(b, o); }
        if (li == 0) {
            sd1[n] = b;
            uint4 rv;
            rv.x = __float_as_uint(a);
            rv.y = f2h(xv[0]) | (f2h(xv[1]) << 16);
            rv.z = f2h(xv[2]) | (f2h(xv[3]) << 16);
            rv.w = f2h(xv[4]);
            *(uint4*)(rec + (size_t)n * 4) = rv;
        }
        return;
    }

    // ---- scatter role ----
    int wid = tid >> 6, lane = tid & 63;
    int base = blockIdx.x * SCT_TILE;
    int tilecnt = ET - base; if (tilecnt > SCT_TILE) tilecnt = SCT_TILE;

    for (int i = tid; i < NBUK; i += 1024) cnt_[i] = 0;
    __syncthreads();
    int sreg[8], dreg[8], rreg[8];
#pragma unroll
    for (int it = 0; it < 2; ++it) {
        int i = base + (it * 1024 + tid) * 4;
        if (i + 3 < EE) {
            const int4 sv = *(const int4*)(ei + i);
            const int4 dv = *(const int4*)(ei + EE + i);
            sreg[it*4+0] = sv.x; sreg[it*4+1] = sv.y; sreg[it*4+2] = sv.z; sreg[it*4+3] = sv.w;
            dreg[it*4+0] = dv.x; dreg[it*4+1] = dv.y; dreg[it*4+2] = dv.z; dreg[it*4+3] = dv.w;
        } else {
#pragma unroll
            for (int k = 0; k < 4; ++k) {
                int idx = i + k;
                if (idx < EE)      { sreg[it*4+k] = ei[idx];  dreg[it*4+k] = ei[EE + idx]; }
                else if (idx < ET) { sreg[it*4+k] = idx - EE; dreg[it*4+k] = idx - EE; }
                else               { dreg[it*4+k] = -1; }
            }
        }
#pragma unroll
        for (int k = 0; k < 4; ++k)
            if (dreg[it*4+k] >= 0) rreg[it*4+k] = atomicAdd(&cnt_[dreg[it*4+k] >> 8], 1);
    }
    __syncthreads();
    int b0 = tid * 4;
    int s0 = 0;
    if (b0 < NBUK)
        for (int k = 0; k < 4 && b0 + k < NBUK; ++k) s0 += cnt_[b0 + k];
    int incl = s0;
#pragma unroll
    for (int o = 1; o < 64; o <<= 1) {
        int t = __shfl(incl, (lane - o) & 63);
        if (lane >= o) incl += t;
    }
    if (lane == 63) wsum[wid] = incl;
    __syncthreads();
    int wpref = 0;
    for (int w = 0; w < wid; ++w) wpref += wsum[w];
    if (b0 < NBUK) {
        int run = wpref + incl - s0;
        for (int k = 0; k < 4 && b0 + k < NBUK; ++k) {
            loc[b0 + k] = run;
            run += cnt_[b0 + k];
        }
    }
    __syncthreads();
    for (int i = tid; i < NBUK; i += 1024) {
        int c = cnt_[i];
        cur[i] = c ? (atomicAdd(&bcur[i], c) + i * BUKCAP - loc[i]) : 0;
    }
    __syncthreads();
#pragma unroll
    for (int q = 0; q < 8; ++q) {
        if (dreg[q] >= 0) {
            int s = sreg[q], d = dreg[q];
            int b = d >> 8;
            int slot = loc[b] + rreg[q];
            sp[slot]  = ((unsigned)(d & 255) << 17) | (unsigned)s;
            bid[slot] = (unsigned short)b;
        }
    }
    __syncthreads();
    for (int i = tid; i < tilecnt; i += 1024)
        pairs[cur[bid[i]] + i] = sp[i];
}

// ---------------- per-bucket counting sort: uint4 reads, 1 rank-atomic/edge, int2 rowcnt ----------------
__global__ __launch_bounds__(1024) void k_bsort(const int* __restrict__ bcur,
                                                unsigned* __restrict__ pairs,
                                                int2* __restrict__ rowcnt) {
    __shared__ int hist[256], sc[256];
    int b = blockIdx.x;
    int cnt = bcur[b];
    if (cnt > BUKCAP) cnt = BUKCAP;
    int base = b * BUKCAP;
    int tid = threadIdx.x;
    if (tid < 256) hist[tid] = 0;
    __syncthreads();
    unsigned preg[8];
    int rreg[8];
    int i0 = tid * 8;
    if (i0 + 8 <= cnt) {
        const uint4 v0 = *(const uint4*)(pairs + base + i0);
        const uint4 v1 = *(const uint4*)(pairs + base + i0 + 4);
        preg[0] = v0.x; preg[1] = v0.y; preg[2] = v0.z; preg[3] = v0.w;
        preg[4] = v1.x; preg[5] = v1.y; preg[6] = v1.z; preg[7] = v1.w;
    } else {
#pragma unroll
        for (int j = 0; j < 8; ++j)
            preg[j] = (i0 + j < cnt) ? pairs[base + i0 + j] : 0xFFFFFFFFu;
    }
#pragma unroll
    for (int j = 0; j < 8; ++j)
        if (preg[j] != 0xFFFFFFFFu) rreg[j] = atomicAdd(&hist[preg[j] >> 17], 1);
    __syncthreads();
    if (tid < 64) {
        int v0 = hist[4 * tid], v1 = hist[4 * tid + 1];
        int v2 = hist[4 * tid + 2], v3 = hist[4 * tid + 3];
        int s = v0 + v1 + v2 + v3;
#pragma unroll
        for (int o = 1; o < 64; o <<= 1) {
            int t = __shfl(s, (tid - o) & 63);
            if (tid >= o) s += t;
        }
        int excl = s - v0 - v1 - v2 - v3;
        sc[4 * tid]     = excl;
        sc[4 * tid + 1] = excl + v0;
        sc[4 * tid + 2] = excl + v0 + v1;
        sc[4 * tid + 3] = excl + v0 + v1 + v2;
    }
    __syncthreads();
    int nbase = b << 8;
    if (tid < 256 && nbase + tid < NN)
        rowcnt[nbase + tid] = make_int2(base + sc[tid], hist[tid]);
    int* adj = (int*)pairs;
#pragma unroll
    for (int j = 0; j < 8; ++j) {
        if (preg[j] != 0xFFFFFFFFu) {
            int ld = (int)(preg[j] >> 17);
            adj[base + sc[ld] + rreg[j]] = (int)(preg[j] & 0x1FFFF);
        }
    }
}

// ---------------- layer 1 generic fallback (deg>32): single pass, no max, 16B record ----------------
__device__ __forceinline__ void agg1_node_gen(int n, int lane, int off, int deg,
                                              const int* __restrict__ adj,
                                              const unsigned* __restrict__ rec,
                                              const float* __restrict__ sd1,
                                              const float* __restrict__ W1,
                                              const float* __restrict__ b1,
                                              const float* __restrict__ W2,
                                              float* __restrict__ h2) {
    float sdn = sd1[n];
    float dsum = 0.f, a0 = 0.f, a1 = 0.f, a2 = 0.f, a3 = 0.f, a4 = 0.f;
    for (int j0 = 0; j0 < deg; j0 += 64) {
        int j = j0 + lane;
        if (j < deg) {
            int s = adj[off + j];
            const uint4 v = *(const uint4*)(rec + (size_t)s * 4);
            float t = __uint_as_float(v.x) + sdn;
            float e = t > 0.f ? t : NEG * t;
            float w = __expf(e);
            dsum += w;
            a0 += w * uh(v.y); a1 += w * uh(v.y >> 16);
            a2 += w * uh(v.z); a3 += w * uh(v.z >> 16);
            a4 += w * uh(v.w);
        }
    }
#pragma unroll
    for (int o = 32; o; o >>= 1) {
        dsum += __shfl_xor(dsum, o);
        a0 += __shfl_xor(a0, o); a1 += __shfl_xor(a1, o); a2 += __shfl_xor(a2, o);
        a3 += __shfl_xor(a3, o); a4 += __shfl_xor(a4, o);
    }
    float inv = 1.0f / dsum;
    a0 *= inv; a1 *= inv; a2 *= inv; a3 *= inv; a4 *= inv;
    float of = b1[lane] + a0 * W1[lane] + a1 * W1[64 + lane] + a2 * W1[128 + lane]
             + a3 * W1[192 + lane] + a4 * W1[256 + lane];
    of = fmaxf(of, 0.f);
    float p2 = of * W2[lane];
#pragma unroll
    for (int o = 32; o; o >>= 1) p2 += __shfl_xor(p2, o);
    if (lane == 0) h2[n] = p2;
}

// ---------------- layer 1: lane=edge, 2 nodes per wave, no max, ONE 16B gather/edge ----------------
__global__ __launch_bounds__(256) void k_agg1(const int* __restrict__ rowcnt,
                                              const int* __restrict__ adj,
                                              const unsigned* __restrict__ rec,
                                              const float* __restrict__ sd1,
                                              const float* __restrict__ W1,
                                              const float* __restrict__ b1,
                                              const float* __restrict__ W2,
                                              float* __restrict__ h2) {
    int wid  = threadIdx.x >> 6;
    int lane = threadIdx.x & 63;
    int n0 = (blockIdx.x * 4 + wid) * 2;
    if (n0 >= NN) return;
    // one 16B load fetches {off0,deg0,off1,deg1}
    const int4 rc = *(const int4*)(rowcnt + n0 * 2);
    int off0 = rc.x, d0 = rc.y, off1 = rc.z, d1 = rc.w;

    if (d0 <= 32 && d1 <= 32) {
        int half = lane >> 5, li = lane & 31;
        int n = n0 + half;
        int off = half ? off1 : off0;
        int deg = half ? d1 : d0;
        float sdn = sd1[n];
        int s = adj[off + (li < deg ? li : 0)];
        const uint4 v = *(const uint4*)(rec + (size_t)s * 4);
        float t = __uint_as_float(v.x) + sdn;
        float e = t > 0.f ? t : NEG * t;
        float p = (li < deg) ? __expf(e) : 0.f;
        float ds = p;
        float a0 = p * uh(v.y), a1 = p * uh(v.y >> 16);
        float a2 = p * uh(v.z), a3 = p * uh(v.z >> 16);
        float a4 = p * uh(v.w);
#pragma unroll
        for (int o = 1; o <= 16; o <<= 1) {
            ds += __shfl_xor(ds, o);
            a0 += __shfl_xor(a0, o); a1 += __shfl_xor(a1, o); a2 += __shfl_xor(a2, o);
            a3 += __shfl_xor(a3, o); a4 += __shfl_xor(a4, o);
        }
        float inv = 1.0f / ds;
        a0 *= inv; a1 *= inv; a2 *= inv; a3 *= inv; a4 *= inv;
        float o0 = b1[li] + a0 * W1[li] + a1 * W1[64 + li] + a2 * W1[128 + li]
                 + a3 * W1[192 + li] + a4 * W1[256 + li];
        float o1 = b1[li + 32] + a0 * W1[li + 32] + a1 * W1[96 + li] + a2 * W1[160 + li]
                 + a3 * W1[224 + li] + a4 * W1[288 + li];
        o0 = fmaxf(o0, 0.f);
        o1 = fmaxf(o1, 0.f);
        float p2 = o0 * W2[li] + o1 * W2[li + 32];
#pragma unroll
        for (int o = 1; o <= 16; o <<= 1) p2 += __shfl_xor(p2, o);
        if (li == 0) h2[n] = p2;
    } else {
        agg1_node_gen(n0,     lane, off0, d0, adj, rec, sd1, W1, b1, W2, h2);
        agg1_node_gen(n0 + 1, lane, off1, d1, adj, rec, sd1, W1, b1, W2, h2);
    }
}

// ---------------- layer 2: full-wave single-node fallback (no max, single pass) ----------------
__device__ __forceinline__ void agg2_node(int n, int lane, int off, int deg,
                                          const int* __restrict__ adj,
                                          const float* __restrict__ h2,
                                          float as2v, float ad2v, float b2v,
                                          float* __restrict__ out) {
    float sdn = h2[n] * ad2v;
    float dsum = 0.f, nsum = 0.f;
    for (int j0 = 0; j0 < deg; j0 += 64) {
        int j = j0 + lane;
        if (j < deg) {
            int s = adj[off + j];
            float hv = h2[s];
            float e = hv * as2v + sdn;
            e = e > 0.f ? e : NEG * e;
            float ex = __expf(e);
            dsum += ex;
            nsum += ex * hv;
        }
    }
#pragma unroll
    for (int o = 32; o; o >>= 1) { dsum += __shfl_xor(dsum, o); nsum += __shfl_xor(nsum, o); }
    if (lane == 0) out[n] = nsum / dsum + b2v;
}

// ---------------- layer 2: 4 nodes per wave, no max ----------------
__global__ __launch_bounds__(256) void k_agg2(const int* __restrict__ rowcnt,
                                              const int* __restrict__ adj,
                                              const float* __restrict__ h2,
                                              const float* __restrict__ as2,
                                              const float* __restrict__ ad2,
                                              const float* __restrict__ b2,
                                              float* __restrict__ out) {
    int wid  = threadIdx.x >> 6;
    int lane = threadIdx.x & 63;
    int n0 = (blockIdx.x * 4 + wid) * 4;
    if (n0 >= NN) return;
    float as2v = as2[0], ad2v = ad2[0], b2v = b2[0];
    const int4 rcA = *(const int4*)(rowcnt + n0 * 2);
    const int4 rcB = *(const int4*)(rowcnt + n0 * 2 + 4);
    int d0 = rcA.y, d1 = rcA.w, d2 = rcB.y, d3 = rcB.w;

    if (d0 <= 32 && d1 <= 32 && d2 <= 32 && d3 <= 32) {
        int half = lane >> 5, li = lane & 31;
        int nA = n0 + half, nB = n0 + 2 + half;
        int offA = half ? rcA.z : rcA.x;
        int offB = half ? rcB.z : rcB.x;
        int degA = half ? d1 : d0, degB = half ? d3 : d2;
        float sdA = h2[nA] * ad2v, sdB = h2[nB] * ad2v;
        float hvA = 0.f, hvB = 0.f, pA = 0.f, pB = 0.f;
        if (li < degA) {
            hvA = h2[adj[offA + li]];
            float t = hvA * as2v + sdA;
            pA = __expf(t > 0.f ? t : NEG * t);
        }
        if (li < degB) {
            hvB = h2[adj[offB + li]];
            float t = hvB * as2v + sdB;
            pB = __expf(t > 0.f ? t : NEG * t);
        }
        float dsA = pA, dsB = pB, nsA = pA * hvA, nsB = pB * hvB;
#pragma unroll
        for (int o = 1; o <= 16; o <<= 1) {
            dsA += __shfl_xor(dsA, o); nsA += __shfl_xor(nsA, o);
            dsB += __shfl_xor(dsB, o); nsB += __shfl_xor(nsB, o);
        }
        if (li == 0) {
            out[nA] = nsA / dsA + b2v;
            out[nB] = nsB / dsB + b2v;
        }
    } else {
        agg2_node(n0,     lane, rcA.x, d0, adj, h2, as2v, ad2v, b2v, out);
        agg2_node(n0 + 1, lane, rcA.z, d1, adj, h2, as2v, ad2v, b2v, out);
        agg2_node(n0 + 2, lane, rcB.x, d2, adj, h2, as2v, ad2v, b2v, out);
        agg2_node(n0 + 3, lane, rcB.z, d3, adj, h2, as2v, ad2v, b2v, out);
    }
}

extern "C" void kernel_launch(void* const* d_in, const int* in_sizes, int n_in,
                              void* d_out, int out_size, void* d_ws, size_t ws_size,
                              hipStream_t stream) {
    const float* x      = (const float*)d_in[0];
    const int*   ei     = (const int*)d_in[1];
    const float* W1     = (const float*)d_in[2];
    const float* a_src1 = (const float*)d_in[3];
    const float* a_dst1 = (const float*)d_in[4];
    const float* b1     = (const float*)d_in[5];
    const float* W2     = (const float*)d_in[6];
    const float* as2    = (const float*)d_in[7];
    const float* ad2    = (const float*)d_in[8];
    const float* b2     = (const float*)d_in[9];
    float* out = (float*)d_out;

    // workspace layout (all 4-byte elements)
    unsigned* rec = (unsigned*)d_ws;                    // N*4 words = 1.6MB
    float* sd1  = (float*)(rec + (size_t)NN * 4);       // N
    float* h2   = sd1 + NN;                             // N
    int2* rowcnt = (int2*)(h2 + NN);                    // N int2 (16B-aligned pairs)
    int* bcur   = (int*)(rowcnt + NN);                  // 1024
    unsigned* pairs = (unsigned*)(bcur + 1024);         // NBUK*BUKCAP = 12.8MB (reused as adj)
    int* adj    = (int*)pairs;

    const int NPAIR = (NN / 2 + 3) / 4;                 // 12500 blocks, 2 nodes/wave
    const int NQUAD = (NN + 15) / 16;                   // 6250 blocks, 4 nodes/wave

    hipMemsetAsync(bcur, 0, 1024 * sizeof(int), stream);
    k_front<<<NSCT + NPROJB, 1024, 0, stream>>>(x, W1, a_src1, a_dst1, ei,
                                                rec, sd1, bcur, pairs);
    k_bsort<<<NBUK, 1024, 0, stream>>>(bcur, pairs, rowcnt);
    k_agg1<<<NPAIR, 256, 0, stream>>>((const int*)rowcnt, adj, rec, sd1, W1, b1, W2, h2);
    k_agg2<<<NQUAD, 256, 0, stream>>>((const int*)rowcnt, adj, h2, as2, ad2, b2, out);
}

// Round 21
// 70.333 us; speedup vs baseline: 1.1338x; 1.0848x over previous
//
#include <hip/hip_runtime.h>
#include <hip/hip_bf16.h>
#include <hip/hip_fp16.h>

#define NN 100000
#define EE 1600000
#define ET (EE + NN)            // edges incl. self loops
#define HID 64
#define NEG 0.2f
#define NBUK 391                // ceil(NN/256) buckets of 256 dst nodes
#define SCT_TILE 8192           // edges per block in scatter phase (1024 thr x 8)
#define BUKCAP 8192             // padded per-bucket capacity (mean 4352, sigma~66)

__device__ __forceinline__ float uh(unsigned u) {
    __half_raw r; r.x = (unsigned short)(u & 0xFFFF);
    return __half2float(__half(r));
}
__device__ __forceinline__ unsigned f2h(float f) {
    __half h = __float2half_rn(f);
    __half_raw r = *reinterpret_cast<__half_raw*>(&h);
    return (unsigned)r.x;
}

#define NSCT ((ET + SCT_TILE - 1) / SCT_TILE)   // 208 scatter-role blocks
#define NPROJB ((NN + 31) / 32)                 // 3125 proj-role blocks (32 nodes each)

// ---------------- merged front kernel: scatter role (blocks < NSCT) + proj role ----------------
__global__ __launch_bounds__(1024) void k_front(const float* __restrict__ x,
                                                const float* __restrict__ W1,
                                                const float* __restrict__ a_src1,
                                                const float* __restrict__ a_dst1,
                                                const int* __restrict__ ei,
                                                unsigned* __restrict__ rec,
                                                float* __restrict__ sd1,
                                                int* __restrict__ bcur,
                                                unsigned* __restrict__ pairs) {
    __shared__ unsigned sp[SCT_TILE];
    __shared__ unsigned short bid[SCT_TILE];
    __shared__ int cnt_[NBUK], loc[NBUK], cur[NBUK];
    __shared__ int wsum[16];
    int tid = threadIdx.x;

    if (blockIdx.x >= NSCT) {
        // ---- proj role: 16 waves x 2 nodes = 32 nodes per block ----
        int p = blockIdx.x - NSCT;
        int wid  = tid >> 6;
        int half = (tid >> 5) & 1, li = tid & 31;
        int n = p * 32 + wid * 2 + half;
        if (n >= NN) return;
        float xv[5];
        float h0 = 0.f, h1 = 0.f;
#pragma unroll
        for (int k = 0; k < 5; ++k) {
            xv[k] = x[n * 5 + k];
            h0 += xv[k] * W1[k * HID + li];
            h1 += xv[k] * W1[k * HID + li + 32];
        }
        float a = h0 * a_src1[li] + h1 * a_src1[li + 32];
        float b = h0 * a_dst1[li] + h1 * a_dst1[li + 32];
#pragma unroll
        for (int o = 1; o <= 16; o <<= 1) { a += __shfl_xor(a, o); b += __shfl_xor(b, o); }
        if (li == 0) {
            sd1[n] = b;
            uint4 rv;
            rv.x = __float_as_uint(a);
            rv.y = f2h(xv[0]) | (f2h(xv[1]) << 16);
            rv.z = f2h(xv[2]) | (f2h(xv[3]) << 16);
            rv.w = f2h(xv[4]);
            *(uint4*)(rec + (size_t)n * 4) = rv;
        }
        return;
    }

    // ---- scatter role ----
    int wid = tid >> 6, lane = tid & 63;
    int base = blockIdx.x * SCT_TILE;
    int tilecnt = ET - base; if (tilecnt > SCT_TILE) tilecnt = SCT_TILE;

    for (int i = tid; i < NBUK; i += 1024) cnt_[i] = 0;
    __syncthreads();
    int sreg[8], dreg[8], rreg[8];
#pragma unroll
    for (int it = 0; it < 2; ++it) {
        int i = base + (it * 1024 + tid) * 4;
        if (i + 3 < EE) {
            const int4 sv = *(const int4*)(ei + i);
            const int4 dv = *(const int4*)(ei + EE + i);
            sreg[it*4+0] = sv.x; sreg[it*4+1] = sv.y; sreg[it*4+2] = sv.z; sreg[it*4+3] = sv.w;
            dreg[it*4+0] = dv.x; dreg[it*4+1] = dv.y; dreg[it*4+2] = dv.z; dreg[it*4+3] = dv.w;
        } else {
#pragma unroll
            for (int k = 0; k < 4; ++k) {
                int idx = i + k;
                if (idx < EE)      { sreg[it*4+k] = ei[idx];  dreg[it*4+k] = ei[EE + idx]; }
                else if (idx < ET) { sreg[it*4+k] = idx - EE; dreg[it*4+k] = idx - EE; }
                else               { dreg[it*4+k] = -1; }
            }
        }
#pragma unroll
        for (int k = 0; k < 4; ++k)
            if (dreg[it*4+k] >= 0) rreg[it*4+k] = atomicAdd(&cnt_[dreg[it*4+k] >> 8], 1);
    }
    __syncthreads();
    int b0 = tid * 4;
    int s0 = 0;
    if (b0 < NBUK)
        for (int k = 0; k < 4 && b0 + k < NBUK; ++k) s0 += cnt_[b0 + k];
    int incl = s0;
#pragma unroll
    for (int o = 1; o < 64; o <<= 1) {
        int t = __shfl(incl, (lane - o) & 63);
        if (lane >= o) incl += t;
    }
    if (lane == 63) wsum[wid] = incl;
    __syncthreads();
    int wpref = 0;
    for (int w = 0; w < wid; ++w) wpref += wsum[w];
    if (b0 < NBUK) {
        int run = wpref + incl - s0;
        for (int k = 0; k < 4 && b0 + k < NBUK; ++k) {
            loc[b0 + k] = run;
            run += cnt_[b0 + k];
        }
    }
    __syncthreads();
    for (int i = tid; i < NBUK; i += 1024) {
        int c = cnt_[i];
        cur[i] = c ? (atomicAdd(&bcur[i], c) + i * BUKCAP - loc[i]) : 0;
    }
    __syncthreads();
#pragma unroll
    for (int q = 0; q < 8; ++q) {
        if (dreg[q] >= 0) {
            int s = sreg[q], d = dreg[q];
            int b = d >> 8;
            int slot = loc[b] + rreg[q];
            sp[slot]  = ((unsigned)(d & 255) << 17) | (unsigned)s;
            bid[slot] = (unsigned short)b;
        }
    }
    __syncthreads();
    for (int i = tid; i < tilecnt; i += 1024)
        pairs[cur[bid[i]] + i] = sp[i];
}

// ---------------- per-bucket counting sort: LDS-staged sort, CONTIGUOUS adj flush ----------------
__global__ __launch_bounds__(1024) void k_bsort(const int* __restrict__ bcur,
                                                unsigned* __restrict__ pairs,
                                                int2* __restrict__ rowcnt) {
    __shared__ int srt[BUKCAP];     // 32KB sorted srcs
    __shared__ int hist[256], sc[256];
    int b = blockIdx.x;
    int cnt = bcur[b];
    if (cnt > BUKCAP) cnt = BUKCAP;
    int base = b * BUKCAP;
    int tid = threadIdx.x;
    if (tid < 256) hist[tid] = 0;
    __syncthreads();
    // pass 1: vectorized read (8 contiguous pairs/thread), rank-atomic, registers
    unsigned preg[8];
    int rreg[8];
    int i0 = tid * 8;
    if (i0 + 8 <= cnt) {
        const uint4 v0 = *(const uint4*)(pairs + base + i0);
        const uint4 v1 = *(const uint4*)(pairs + base + i0 + 4);
        preg[0] = v0.x; preg[1] = v0.y; preg[2] = v0.z; preg[3] = v0.w;
        preg[4] = v1.x; preg[5] = v1.y; preg[6] = v1.z; preg[7] = v1.w;
    } else {
#pragma unroll
        for (int j = 0; j < 8; ++j)
            preg[j] = (i0 + j < cnt) ? pairs[base + i0 + j] : 0xFFFFFFFFu;
    }
#pragma unroll
    for (int j = 0; j < 8; ++j)
        if (preg[j] != 0xFFFFFFFFu) rreg[j] = atomicAdd(&hist[preg[j] >> 17], 1);
    __syncthreads();
    // 256-bin exclusive scan on wave 0 (4 bins/lane)
    if (tid < 64) {
        int v0 = hist[4 * tid], v1 = hist[4 * tid + 1];
        int v2 = hist[4 * tid + 2], v3 = hist[4 * tid + 3];
        int s = v0 + v1 + v2 + v3;
#pragma unroll
        for (int o = 1; o < 64; o <<= 1) {
            int t = __shfl(s, (tid - o) & 63);
            if (tid >= o) s += t;
        }
        int excl = s - v0 - v1 - v2 - v3;
        sc[4 * tid]     = excl;
        sc[4 * tid + 1] = excl + v0;
        sc[4 * tid + 2] = excl + v0 + v1;
        sc[4 * tid + 3] = excl + v0 + v1 + v2;
    }
    __syncthreads();
    int nbase = b << 8;
    if (tid < 256 && nbase + tid < NN)
        rowcnt[nbase + tid] = make_int2(base + sc[tid], hist[tid]);
    // scatter into LDS (cheap: <=2-way bank aliasing), then flush contiguously
#pragma unroll
    for (int j = 0; j < 8; ++j) {
        if (preg[j] != 0xFFFFFFFFu) {
            int ld = (int)(preg[j] >> 17);
            srt[sc[ld] + rreg[j]] = (int)(preg[j] & 0x1FFFF);
        }
    }
    __syncthreads();
    int* adj = (int*)pairs;   // aliases pairs; all pairs reads completed above
    for (int i = tid; i < cnt; i += 1024)
        adj[base + i] = srt[i];
}

// ---------------- layer 1 generic fallback (deg>32): single pass, no max, 16B record ----------------
__device__ __forceinline__ void agg1_node_gen(int n, int lane, int off, int deg,
                                              const int* __restrict__ adj,
                                              const unsigned* __restrict__ rec,
                                              const float* __restrict__ sd1,
                                              const float* __restrict__ W1,
                                              const float* __restrict__ b1,
                                              const float* __restrict__ W2,
                                              float* __restrict__ h2) {
    float sdn = sd1[n];
    float dsum = 0.f, a0 = 0.f, a1 = 0.f, a2 = 0.f, a3 = 0.f, a4 = 0.f;
    for (int j0 = 0; j0 < deg; j0 += 64) {
        int j = j0 + lane;
        if (j < deg) {
            int s = adj[off + j];
            const uint4 v = *(const uint4*)(rec + (size_t)s * 4);
            float t = __uint_as_float(v.x) + sdn;
            float e = t > 0.f ? t : NEG * t;
            float w = __expf(e);
            dsum += w;
            a0 += w * uh(v.y); a1 += w * uh(v.y >> 16);
            a2 += w * uh(v.z); a3 += w * uh(v.z >> 16);
            a4 += w * uh(v.w);
        }
    }
#pragma unroll
    for (int o = 32; o; o >>= 1) {
        dsum += __shfl_xor(dsum, o);
        a0 += __shfl_xor(a0, o); a1 += __shfl_xor(a1, o); a2 += __shfl_xor(a2, o);
        a3 += __shfl_xor(a3, o); a4 += __shfl_xor(a4, o);
    }
    float inv = 1.0f / dsum;
    a0 *= inv; a1 *= inv; a2 *= inv; a3 *= inv; a4 *= inv;
    float of = b1[lane] + a0 * W1[lane] + a1 * W1[64 + lane] + a2 * W1[128 + lane]
             + a3 * W1[192 + lane] + a4 * W1[256 + lane];
    of = fmaxf(of, 0.f);
    float p2 = of * W2[lane];
#pragma unroll
    for (int o = 32; o; o >>= 1) p2 += __shfl_xor(p2, o);
    if (lane == 0) h2[n] = p2;
}

// ---------------- layer 1: lane=edge, 2 nodes per wave, no max, ONE 16B gather/edge ----------------
__global__ __launch_bounds__(256) void k_agg1(const int* __restrict__ rowcnt,
                                              const int* __restrict__ adj,
                                              const unsigned* __restrict__ rec,
                                              const float* __restrict__ sd1,
                                              const float* __restrict__ W1,
                                              const float* __restrict__ b1,
                                              const float* __restrict__ W2,
                                              float* __restrict__ h2) {
    int wid  = threadIdx.x >> 6;
    int lane = threadIdx.x & 63;
    int n0 = (blockIdx.x * 4 + wid) * 2;
    if (n0 >= NN) return;
    const int4 rc = *(const int4*)(rowcnt + n0 * 2);
    int off0 = rc.x, d0 = rc.y, off1 = rc.z, d1 = rc.w;

    if (d0 <= 32 && d1 <= 32) {
        int half = lane >> 5, li = lane & 31;
        int n = n0 + half;
        int off = half ? off1 : off0;
        int deg = half ? d1 : d0;
        float sdn = sd1[n];
        int s = adj[off + (li < deg ? li : 0)];
        const uint4 v = *(const uint4*)(rec + (size_t)s * 4);
        float t = __uint_as_float(v.x) + sdn;
        float e = t > 0.f ? t : NEG * t;
        float p = (li < deg) ? __expf(e) : 0.f;
        float ds = p;
        float a0 = p * uh(v.y), a1 = p * uh(v.y >> 16);
        float a2 = p * uh(v.z), a3 = p * uh(v.z >> 16);
        float a4 = p * uh(v.w);
#pragma unroll
        for (int o = 1; o <= 16; o <<= 1) {
            ds += __shfl_xor(ds, o);
            a0 += __shfl_xor(a0, o); a1 += __shfl_xor(a1, o); a2 += __shfl_xor(a2, o);
            a3 += __shfl_xor(a3, o); a4 += __shfl_xor(a4, o);
        }
        float inv = 1.0f / ds;
        a0 *= inv; a1 *= inv; a2 *= inv; a3 *= inv; a4 *= inv;
        float o0 = b1[li] + a0 * W1[li] + a1 * W1[64 + li] + a2 * W1[128 + li]
                 + a3 * W1[192 + li] + a4 * W1[256 + li];
        float o1 = b1[li + 32] + a0 * W1[li + 32] + a1 * W1[96 + li] + a2 * W1[160 + li]
                 + a3 * W1[224 + li] + a4 * W1[288 + li];
        o0 = fmaxf(o0, 0.f);
        o1 = fmaxf(o1, 0.f);
        float p2 = o0 * W2[li] + o1 * W2[li + 32];
#pragma unroll
        for (int o = 1; o <= 16; o <<= 1) p2 += __shfl_xor(p2, o);
        if (li == 0) h2[n] = p2;
    } else {
        agg1_node_gen(n0,     lane, off0, d0, adj, rec, sd1, W1, b1, W2, h2);
        agg1_node_gen(n0 + 1, lane, off1, d1, adj, rec, sd1, W1, b1, W2, h2);
    }
}

// ---------------- layer 2: full-wave single-node fallback (no max, single pass) ----------------
__device__ __forceinline__ void agg2_node(int n, int lane, int off, int deg,
                                          const int* __restrict__ adj,
                                          const float* __restrict__ h2,
                                          float as2v, float ad2v, float b2v,
                                          float* __restrict__ out) {
    float sdn = h2[n] * ad2v;
    float dsum = 0.f, nsum = 0.f;
    for (int j0 = 0; j0 < deg; j0 += 64) {
        int j = j0 + lane;
        if (j < deg) {
            int s = adj[off + j];
            float hv = h2[s];
            float e = hv * as2v + sdn;
            e = e > 0.f ? e : NEG * e;
            float ex = __expf(e);
            dsum += ex;
            nsum += ex * hv;
        }
    }
#pragma unroll
    for (int o = 32; o; o >>= 1) { dsum += __shfl_xor(dsum, o); nsum += __shfl_xor(nsum, o); }
    if (lane == 0) out[n] = nsum / dsum + b2v;
}

// ---------------- layer 2: 4 nodes per wave, no max ----------------
__global__ __launch_bounds__(256) void k_agg2(const int* __restrict__ rowcnt,
                                              const int* __restrict__ adj,
                                              const float* __restrict__ h2,
                                              const float* __restrict__ as2,
                                              const float* __restrict__ ad2,
                                              const float* __restrict__ b2,
                                              float* __restrict__ out) {
    int wid  = threadIdx.x >> 6;
    int lane = threadIdx.x & 63;
    int n0 = (blockIdx.x * 4 + wid) * 4;
    if (n0 >= NN) return;
    float as2v = as2[0], ad2v = ad2[0], b2v = b2[0];
    const int4 rcA = *(const int4*)(rowcnt + n0 * 2);
    const int4 rcB = *(const int4*)(rowcnt + n0 * 2 + 4);
    int d0 = rcA.y, d1 = rcA.w, d2 = rcB.y, d3 = rcB.w;

    if (d0 <= 32 && d1 <= 32 && d2 <= 32 && d3 <= 32) {
        int half = lane >> 5, li = lane & 31;
        int nA = n0 + half, nB = n0 + 2 + half;
        int offA = half ? rcA.z : rcA.x;
        int offB = half ? rcB.z : rcB.x;
        int degA = half ? d1 : d0, degB = half ? d3 : d2;
        float sdA = h2[nA] * ad2v, sdB = h2[nB] * ad2v;
        float hvA = 0.f, hvB = 0.f, pA = 0.f, pB = 0.f;
        if (li < degA) {
            hvA = h2[adj[offA + li]];
            float t = hvA * as2v + sdA;
            pA = __expf(t > 0.f ? t : NEG * t);
        }
        if (li < degB) {
            hvB = h2[adj[offB + li]];
            float t = hvB * as2v + sdB;
            pB = __expf(t > 0.f ? t : NEG * t);
        }
        float dsA = pA, dsB = pB, nsA = pA * hvA, nsB = pB * hvB;
#pragma unroll
        for (int o = 1; o <= 16; o <<= 1) {
            dsA += __shfl_xor(dsA, o); nsA += __shfl_xor(nsA, o);
            dsB += __shfl_xor(dsB, o); nsB += __shfl_xor(nsB, o);
        }
        if (li == 0) {
            out[nA] = nsA / dsA + b2v;
            out[nB] = nsB / dsB + b2v;
        }
    } else {
        agg2_node(n0,     lane, rcA.x, d0, adj, h2, as2v, ad2v, b2v, out);
        agg2_node(n0 + 1, lane, rcA.z, d1, adj, h2, as2v, ad2v, b2v, out);
        agg2_node(n0 + 2, lane, rcB.x, d2, adj, h2, as2v, ad2v, b2v, out);
        agg2_node(n0 + 3, lane, rcB.z, d3, adj, h2, as2v, ad2v, b2v, out);
    }
}

extern "C" void kernel_launch(void* const* d_in, const int* in_sizes, int n_in,
                              void* d_out, int out_size, void* d_ws, size_t ws_size,
                              hipStream_t stream) {
    const float* x      = (const float*)d_in[0];
    const int*   ei     = (const int*)d_in[1];
    const float* W1     = (const float*)d_in[2];
    const float* a_src1 = (const float*)d_in[3];
    const float* a_dst1 = (const float*)d_in[4];
    const float* b1     = (const float*)d_in[5];
    const float* W2     = (const float*)d_in[6];
    const float* as2    = (const float*)d_in[7];
    const float* ad2    = (const float*)d_in[8];
    const float* b2     = (const float*)d_in[9];
    float* out = (float*)d_out;

    // workspace layout (all 4-byte elements)
    unsigned* rec = (unsigned*)d_ws;                    // N*4 words = 1.6MB
    float* sd1  = (float*)(rec + (size_t)NN * 4);       // N
    float* h2   = sd1 + NN;                             // N
    int2* rowcnt = (int2*)(h2 + NN);                    // N int2 (16B-aligned pairs)
    int* bcur   = (int*)(rowcnt + NN);                  // 1024
    unsigned* pairs = (unsigned*)(bcur + 1024);         // NBUK*BUKCAP = 12.8MB (reused as adj)
    int* adj    = (int*)pairs;

    const int NPAIR = (NN / 2 + 3) / 4;                 // 12500 blocks, 2 nodes/wave
    const int NQUAD = (NN + 15) / 16;                   // 6250 blocks, 4 nodes/wave

    hipMemsetAsync(bcur, 0, 1024 * sizeof(int), stream);
    k_front<<<NSCT + NPROJB, 1024, 0, stream>>>(x, W1, a_src1, a_dst1, ei,
                                                rec, sd1, bcur, pairs);
    k_bsort<<<NBUK, 1024, 0, stream>>>(bcur, pairs, rowcnt);
    k_agg1<<<NPAIR, 256, 0, stream>>>((const int*)rowcnt, adj, rec, sd1, W1, b1, W2, h2);
    k_agg2<<<NQUAD, 256, 0, stream>>>((const int*)rowcnt, adj, h2, as2, ad2, b2, out);
}